// Round 10
// baseline (196.660 us; speedup 1.0000x reference)
//
#include <hip/hip_runtime.h>
#include <hip/hip_bf16.h>

typedef __bf16 bf16_t;
typedef bf16_t bf16x8 __attribute__((ext_vector_type(8)));
typedef float f32x4 __attribute__((ext_vector_type(4)));
typedef float f32x2 __attribute__((ext_vector_type(2)));
typedef float f32x16 __attribute__((ext_vector_type(16)));

#define EMB 1024
#define HEADS 16
#define BATCH 2
#define SEQ 2048
#define HD 64
#define TOKENS (BATCH * SEQ)  // 4096

// async global->LDS, 16B per lane. LDS dest = wave-uniform base + lane*16.
__device__ __forceinline__ void gld16(bf16_t* lds_dst, const bf16_t* g_src) {
    __builtin_amdgcn_global_load_lds(
        (const __attribute__((address_space(1))) unsigned int*)g_src,
        (__attribute__((address_space(3))) unsigned int*)lds_dst, 16, 0, 0);
}

__device__ __forceinline__ unsigned cvt_pk_bf16(float lo, float hi) {
    unsigned r;
    asm("v_cvt_pk_bf16_f32 %0, %1, %2" : "=v"(r) : "v"(lo), "v"(hi));
    return r;
}

// 2^x. Q is pre-scaled by log2(e)/32 in the QKV GEMM, so softmax needs only 2^x.
__device__ __forceinline__ float exp2_fast(float x) {
#if __has_builtin(__builtin_amdgcn_exp2f)
    return __builtin_amdgcn_exp2f(x);
#else
    return __expf(x * 0.69314718056f);
#endif
}

// counted waits: keep prefetches in flight across raw barriers (T4).
#define WAITV(N) asm volatile("s_waitcnt vmcnt(" #N ")" ::: "memory")
#define WAITLGKM() asm volatile("s_waitcnt lgkmcnt(0)" ::: "memory")
#define BAR() __builtin_amdgcn_s_barrier()

// ---------------------------------------------------------------------------
// Merged prep: bid<1024 -> x fp32->bf16 (16 elems/thread);
//              bid>=1024 -> W[k][n] fp32 -> Wt[n][k] bf16 (64x64 tiles).
// ---------------------------------------------------------------------------
__global__ __launch_bounds__(256) void prep_all(
    const float* __restrict__ x, bf16_t* __restrict__ xb,
    const float* __restrict__ W0, const float* __restrict__ W1,
    const float* __restrict__ W2, const float* __restrict__ W3,
    bf16_t* __restrict__ T0, bf16_t* __restrict__ T1,
    bf16_t* __restrict__ T2, bf16_t* __restrict__ T3) {
    __shared__ __align__(16) bf16_t T[64][72];
    if (blockIdx.x < 1024) {
        size_t i = ((size_t)blockIdx.x * 256 + threadIdx.x) * 16;
        f32x4 v0 = *(const f32x4*)&x[i];
        f32x4 v1 = *(const f32x4*)&x[i + 4];
        f32x4 v2 = *(const f32x4*)&x[i + 8];
        f32x4 v3 = *(const f32x4*)&x[i + 12];
        bf16x8 o0, o1;
#pragma unroll
        for (int j = 0; j < 4; ++j) {
            o0[j] = (bf16_t)v0[j]; o0[4 + j] = (bf16_t)v1[j];
            o1[j] = (bf16_t)v2[j]; o1[4 + j] = (bf16_t)v3[j];
        }
        *(bf16x8*)&xb[i] = o0;
        *(bf16x8*)&xb[i + 8] = o1;
        return;
    }
    int t = blockIdx.x - 1024;
    int z = t >> 8, rid = t & 255;
    const float* src = (z == 0) ? W0 : (z == 1) ? W1 : (z == 2) ? W2 : W3;
    bf16_t* dst = (z == 0) ? T0 : (z == 1) ? T1 : (z == 2) ? T2 : T3;
    int k0 = (rid >> 4) * 64, n0 = (rid & 15) * 64;
    int r = threadIdx.x >> 2, c4 = (threadIdx.x & 3) * 16;
    f32x4 v[4];
#pragma unroll
    for (int q = 0; q < 4; ++q)
        v[q] = *(const f32x4*)&src[(size_t)(k0 + r) * 1024 + n0 + c4 + q * 4];
#pragma unroll
    for (int j = 0; j < 16; ++j) T[c4 + j][r] = (bf16_t)v[j >> 2][j & 3];
    __syncthreads();
    bf16x8 o0 = *(const bf16x8*)&T[r][c4];
    bf16x8 o1 = *(const bf16x8*)&T[r][c4 + 8];
    *(bf16x8*)&dst[(size_t)(n0 + r) * 1024 + k0 + c4] = o0;
    *(bf16x8*)&dst[(size_t)(n0 + r) * 1024 + k0 + c4 + 8] = o1;
}

// ---------------------------------------------------------------------------
// gemm8p: m201-style 8-phase GEMM. BM=BN=256 BK=64, 512 thr (8 waves 2Mx4N,
// wave tile 128x64). LDS = 2 bufs x (A 32K + B 32K) = 128 KB. (unchanged R8)
// ---------------------------------------------------------------------------
template <typename TO>
__global__ __launch_bounds__(512) void gemm8p(
    const bf16_t* __restrict__ A, const bf16_t* __restrict__ W,
    const float* __restrict__ b0, const float* __restrict__ b1, const float* __restrict__ b2,
    TO* __restrict__ o0, TO* __restrict__ o1, TO* __restrict__ o2,
    int md0, int md1, int md2, float sc0, float sc1, float sc2,
    int XMP, int XNP, int CXM, int CXS) {
    __shared__ __align__(16) bf16_t As[2][256 * 64];  // 64 KB
    __shared__ __align__(16) bf16_t Bs[2][256 * 64];  // 64 KB

    const int tid = threadIdx.x, w = tid >> 6, lane = tid & 63;
    const int quad = lane >> 4, cc = lane & 15;
    const int wr = w >> 2, wc = w & 3;  // 2M x 4N

    const int lin = blockIdx.x;
    const int xc = lin & 7, t = lin >> 3;
    const int mi = (xc & CXM) * XMP + (t % XMP);
    const int ni = (xc >> CXS) * XNP + (t / XMP);
    const int m0 = mi * 256, n0 = ni * 256;

    const int z = n0 >> 10;
    const float* bias = (z == 0) ? b0 : (z == 1) ? b1 : b2;
    TO* out = (z == 0) ? o0 : (z == 1) ? o1 : o2;
    const int mode = (z == 0) ? md0 : (z == 1) ? md1 : md2;
    const float scale = (z == 0) ? sc0 : (z == 1) ? sc1 : sc2;
    const int nz = n0 & 1023;

    f32x4 acc[8][4];
#pragma unroll
    for (int i = 0; i < 8; ++i)
#pragma unroll
        for (int j = 0; j < 4; ++j) acc[i][j] = (f32x4){0.f, 0.f, 0.f, 0.f};

    const int r8 = lane >> 3, sg = lane & 7;
    const int g8 = (sg ^ r8) * 8;  // pre-swizzled source chunk offset (elems)
    const bf16_t* Ag = A + (size_t)m0 * 1024;
    const bf16_t* Bg = W + (size_t)n0 * 1024;

#define ST_A(BUF, TILE, H)                                                     \
    {                                                                          \
        _Pragma("unroll")                                                      \
        for (int s = 0; s < 2; ++s) {                                          \
            int rg = (H) * 128 + (w * 2 + s) * 8;                              \
            gld16(&As[BUF][rg * 64],                                           \
                  &Ag[(size_t)(rg + r8) * 1024 + (TILE) * 64 + g8]);           \
        }                                                                      \
    }
#define ST_B(BUF, TILE, H)                                                     \
    {                                                                          \
        _Pragma("unroll")                                                      \
        for (int s = 0; s < 2; ++s) {                                          \
            int rg = (H) * 128 + (w * 2 + s) * 8;                              \
            gld16(&Bs[BUF][rg * 64],                                           \
                  &Bg[(size_t)(rg + r8) * 1024 + (TILE) * 64 + g8]);           \
        }                                                                      \
    }

    const int soq = (quad ^ (cc & 7)) * 8;
    int rArow[8], rBrow[4];
#pragma unroll
    for (int mt = 0; mt < 8; ++mt) rArow[mt] = (wr * 128 + mt * 16 + cc) * 64;
#pragma unroll
    for (int nt = 0; nt < 4; ++nt) rBrow[nt] = (wc * 64 + nt * 16 + cc) * 64;

    bf16x8 bfr[4][2];
#define RD_B(BUF)                                                              \
    {                                                                          \
        _Pragma("unroll")                                                      \
        for (int nt = 0; nt < 4; ++nt) {                                       \
            bfr[nt][0] = *(const bf16x8*)&Bs[BUF][rBrow[nt] + soq];            \
            bfr[nt][1] = *(const bf16x8*)&Bs[BUF][rBrow[nt] + (soq ^ 32)];     \
        }                                                                      \
    }

#define PHASE(BUF, Q, STG)                                                     \
    {                                                                          \
        bf16x8 af0a = *(const bf16x8*)&As[BUF][rArow[(Q) * 2] + soq];          \
        bf16x8 af0b = *(const bf16x8*)&As[BUF][rArow[(Q) * 2] + (soq ^ 32)];   \
        bf16x8 af1a = *(const bf16x8*)&As[BUF][rArow[(Q) * 2 + 1] + soq];      \
        bf16x8 af1b = *(const bf16x8*)&As[BUF][rArow[(Q) * 2 + 1] + (soq ^ 32)]; \
        STG;                                                                   \
        WAITLGKM();                                                            \
        __builtin_amdgcn_sched_barrier(0);                                     \
        __builtin_amdgcn_s_setprio(1);                                         \
        _Pragma("unroll")                                                      \
        for (int nt = 0; nt < 4; ++nt) {                                       \
            acc[(Q) * 2][nt] = __builtin_amdgcn_mfma_f32_16x16x32_bf16(        \
                af0a, bfr[nt][0], acc[(Q) * 2][nt], 0, 0, 0);                  \
            acc[(Q) * 2][nt] = __builtin_amdgcn_mfma_f32_16x16x32_bf16(        \
                af0b, bfr[nt][1], acc[(Q) * 2][nt], 0, 0, 0);                  \
            acc[(Q) * 2 + 1][nt] = __builtin_amdgcn_mfma_f32_16x16x32_bf16(    \
                af1a, bfr[nt][0], acc[(Q) * 2 + 1][nt], 0, 0, 0);              \
            acc[(Q) * 2 + 1][nt] = __builtin_amdgcn_mfma_f32_16x16x32_bf16(    \
                af1b, bfr[nt][1], acc[(Q) * 2 + 1][nt], 0, 0, 0);              \
        }                                                                      \
        __builtin_amdgcn_s_setprio(0);                                         \
    }

    ST_A(0, 0, 0) ST_A(0, 0, 1) ST_B(0, 0, 0) ST_B(0, 0, 1)
    ST_B(1, 1, 0) ST_B(1, 1, 1)

    for (int i = 0; i < 8; ++i) {
        WAITV(4);
        BAR();
        RD_B(0)
        PHASE(0, 0, ST_A(1, 2 * i + 1, 0))
        BAR();
        PHASE(0, 1, ST_A(1, 2 * i + 1, 1))
        BAR();
        PHASE(0, 2, if (i < 7) ST_B(0, 2 * i + 2, 0))
        BAR();
        PHASE(0, 3, if (i < 7) ST_B(0, 2 * i + 2, 1))
        if (i < 7) { WAITV(4); } else { WAITV(0); }
        BAR();
        RD_B(1)
        PHASE(1, 0, if (i < 7) ST_A(0, 2 * i + 2, 0))
        BAR();
        PHASE(1, 1, if (i < 7) ST_A(0, 2 * i + 2, 1))
        BAR();
        PHASE(1, 2, if (i < 7) ST_B(1, 2 * i + 3, 0))
        BAR();
        PHASE(1, 3, if (i < 7) ST_B(1, 2 * i + 3, 1))
    }
#undef PHASE
#undef RD_B
#undef ST_A
#undef ST_B

    typedef TO TOx4 __attribute__((ext_vector_type(4)));
#pragma unroll
    for (int nt = 0; nt < 4; ++nt) {
        int colz = nz + wc * 64 + nt * 16 + cc;
        float bv = bias[colz];
#pragma unroll
        for (int mt = 0; mt < 8; ++mt) {
            if (mode == 2) {
                int row = m0 + wr * 128 + mt * 16 + quad * 4;
                int bb = row >> 11, n = row & 2047;
                int hh = colz >> 6, d = colz & 63;
                TOx4 pk;
#pragma unroll
                for (int r = 0; r < 4; ++r)
                    pk[r] = (TO)((acc[mt][nt][r] + bv) * scale);
                *(TOx4*)&out[((size_t)(bb * HEADS + hh) * HD + d) * SEQ + n] = pk;
            } else {
#pragma unroll
                for (int r = 0; r < 4; ++r) {
                    int row = m0 + wr * 128 + mt * 16 + quad * 4 + r;
                    float v = (acc[mt][nt][r] + bv) * scale;
                    size_t idx;
                    if (mode == 0) {
                        idx = (size_t)row * 1024 + colz;
                    } else {
                        int bb = row >> 11, n = row & 2047;
                        int hh = colz >> 6, d = colz & 63;
                        idx = ((size_t)(bb * HEADS + hh) * SEQ + n) * HD + d;
                    }
                    out[idx] = (TO)v;
                }
            }
        }
    }
}

// ---------------------------------------------------------------------------
// GEMM v2 (kept for O-proj): BM=256 BN=128 BK=64, 512 thr, 3 bufs, vmcnt(6).
// ---------------------------------------------------------------------------
template <typename TO>
__global__ __launch_bounds__(512) void gemm256(
    const bf16_t* __restrict__ A, const bf16_t* __restrict__ W,
    const float* __restrict__ b0, const float* __restrict__ b1, const float* __restrict__ b2,
    TO* __restrict__ o0, TO* __restrict__ o1, TO* __restrict__ o2,
    int md0, int md1, int md2, float sc0, float sc1, float sc2,
    int MP, int CM, int CSH, int NP) {
    __shared__ __align__(16) bf16_t As[3][256 * 64];  // 96 KB
    __shared__ __align__(16) bf16_t Bs[3][128 * 64];  // 48 KB

    const int tid = threadIdx.x, w = tid >> 6, lane = tid & 63;
    const int quad = lane >> 4, c = lane & 15;
    const int wm = (w >> 1) * 64, wn = (w & 1) * 64;

    const int lin = blockIdx.x;
    const int xc = lin & 7, t = lin >> 3;
    const int mi = MP * (xc & CM) + (t % MP);
    const int ni = NP * (xc >> CSH) + (t / MP);
    const int m0 = mi * 256, n0 = ni * 128;

    const int z = n0 >> 10;
    const float* bias = (z == 0) ? b0 : (z == 1) ? b1 : b2;
    TO* out = (z == 0) ? o0 : (z == 1) ? o1 : o2;
    const int mode = (z == 0) ? md0 : (z == 1) ? md1 : md2;
    const float scale = (z == 0) ? sc0 : (z == 1) ? sc1 : sc2;
    const int nz = n0 & 1023;

    f32x4 acc[4][4];
#pragma unroll
    for (int i = 0; i < 4; ++i)
#pragma unroll
        for (int j = 0; j < 4; ++j) acc[i][j] = (f32x4){0.f, 0.f, 0.f, 0.f};

    const int r8 = lane >> 3, sg = lane & 7;
    const int g8 = (sg ^ r8) * 8;
    const bf16_t* Ag = A + (size_t)m0 * 1024;
    const bf16_t* Bg = W + (size_t)n0 * 1024;
    int gA[4], lA[4], gB[2], lB[2];
#pragma unroll
    for (int s = 0; s < 4; ++s) {
        lA[s] = (w * 32 + s * 8) * 64;
        gA[s] = (w * 32 + s * 8 + r8) * 1024 + g8;
    }
#pragma unroll
    for (int s = 0; s < 2; ++s) {
        lB[s] = (w * 16 + s * 8) * 64;
        gB[s] = (w * 16 + s * 8 + r8) * 1024 + g8;
    }

    const int so = (quad ^ (c & 7)) * 8;
    int rA[4], rB[4];
#pragma unroll
    for (int i = 0; i < 4; ++i) {
        rA[i] = (wm + i * 16 + c) * 64;
        rB[i] = (wn + i * 16 + c) * 64;
    }

#define STAGE(BUF, T)                                                          \
    {                                                                          \
        int kn = (T) * 64;                                                     \
        _Pragma("unroll")                                                      \
        for (int s = 0; s < 4; ++s) gld16(&As[BUF][lA[s]], &Ag[gA[s] + kn]);   \
        _Pragma("unroll")                                                      \
        for (int s = 0; s < 2; ++s) gld16(&Bs[BUF][lB[s]], &Bg[gB[s] + kn]);   \
    }

#define FRAGS(CUR)                                                             \
    {                                                                          \
        _Pragma("unroll")                                                      \
        for (int ks = 0; ks < 2; ++ks) {                                       \
            int sk = so ^ (ks << 5);                                           \
            bf16x8 af[4], bfv[4];                                              \
            _Pragma("unroll")                                                  \
            for (int i = 0; i < 4; ++i)                                        \
                af[i] = *(const bf16x8*)&As[CUR][rA[i] + sk];                  \
            _Pragma("unroll")                                                  \
            for (int i = 0; i < 4; ++i)                                        \
                bfv[i] = *(const bf16x8*)&Bs[CUR][rB[i] + sk];                 \
            __builtin_amdgcn_s_setprio(1);                                     \
            _Pragma("unroll")                                                  \
            for (int mt = 0; mt < 4; ++mt)                                     \
                _Pragma("unroll")                                              \
                for (int nt = 0; nt < 4; ++nt)                                 \
                    acc[mt][nt] = __builtin_amdgcn_mfma_f32_16x16x32_bf16(     \
                        af[mt], bfv[nt], acc[mt][nt], 0, 0, 0);                \
            __builtin_amdgcn_s_setprio(0);                                     \
        }                                                                      \
    }

#define GSTEP(T, CUR)                                                          \
    {                                                                          \
        WAITV(6);                                                              \
        BAR();                                                                 \
        STAGE(((CUR) + 2) % 3, (T) + 2)                                        \
        FRAGS(CUR)                                                             \
    }

    STAGE(0, 0)
    STAGE(1, 1)
    for (int T = 0; T < 12; T += 3) {
        GSTEP(T, 0)
        GSTEP(T + 1, 1)
        GSTEP(T + 2, 2)
    }
    GSTEP(12, 0)
    GSTEP(13, 1)
    WAITV(6); BAR(); FRAGS(2)
    WAITV(0); BAR(); FRAGS(0)
#undef GSTEP
#undef FRAGS
#undef STAGE

    typedef TO TOx4 __attribute__((ext_vector_type(4)));
#pragma unroll
    for (int nt = 0; nt < 4; ++nt) {
        int colz = nz + wn + nt * 16 + c;
        float bv = bias[colz];
#pragma unroll
        for (int mt = 0; mt < 4; ++mt) {
            if (mode == 2) {
                int row = m0 + wm + mt * 16 + quad * 4;
                int bb = row >> 11, n = row & 2047;
                int hh = colz >> 6, d = colz & 63;
                TOx4 pk;
#pragma unroll
                for (int r = 0; r < 4; ++r)
                    pk[r] = (TO)((acc[mt][nt][r] + bv) * scale);
                *(TOx4*)&out[((size_t)(bb * HEADS + hh) * HD + d) * SEQ + n] = pk;
            } else {
#pragma unroll
                for (int r = 0; r < 4; ++r) {
                    int row = m0 + wm + mt * 16 + quad * 4 + r;
                    float v = (acc[mt][nt][r] + bv) * scale;
                    size_t idx;
                    if (mode == 0) {
                        idx = (size_t)row * 1024 + colz;
                    } else {
                        int bb = row >> 11, n = row & 2047;
                        int hh = colz >> 6, d = colz & 63;
                        idx = ((size_t)(bb * HEADS + hh) * SEQ + n) * HD + d;
                    }
                    out[idx] = (TO)v;
                }
            }
        }
    }
}

// ---------------------------------------------------------------------------
// Flash attention R9 (resubmit): 64 q-rows per wave (2 Q-halves) -> each K/V
// LDS read feeds 2 MFMAs, halving per-work LDS traffic (measured bottleneck).
// Block = 4 waves x 64 q = 256 q-rows; grid (8,32) = 256 blocks = 1/CU.
// ~330 VGPR at 1 wave/SIMD (launch_bounds(256,1); 512-reg unified file).
// KVBLK=128/phase (2 tiles), 16 phases, dbuf, counted waits as R8.
// ---------------------------------------------------------------------------
__global__ __launch_bounds__(256, 1) void attn_kernel(
    const bf16_t* __restrict__ Q, const bf16_t* __restrict__ K,
    const bf16_t* __restrict__ Vt, bf16_t* __restrict__ O) {
    __shared__ __align__(16) bf16_t Ks[2][2 * 64 * 64];   // 32 KB
    __shared__ __align__(16) bf16_t Vs[2][2 * 64 * 64];   // 32 KB

    const int tid = threadIdx.x, w = tid >> 6, lane = tid & 63;
    const int hi = lane >> 5, lq = lane & 31;

    // XCD remap: 256 blocks; xcd = lin&7; 4 bh x 8 q-blocks per XCD.
    const int lin = blockIdx.x + (blockIdx.y << 3);
    const int xcd = lin & 7, slot = lin >> 3;
    const int bh = xcd + ((slot >> 3) << 3);
    const int q0 = (slot & 7) << 8;       // 256 q-rows per block
    const int b = bh >> 4, h = bh & 15;

    const int srow8 = lane >> 3, sch = lane & 7;

    const bf16_t* Kg0 = K + (size_t)bh * SEQ * HD;
    const bf16_t* Vg0 = Vt + (size_t)bh * HD * SEQ;

    int sl[2], sgK[2], sgV[2];
#pragma unroll
    for (int s = 0; s < 2; ++s) {
        int rg = (w * 2 + s) * 8;
        int row = rg + srow8;
        int g = sch ^ (row & 7);
        sl[s] = rg * 64;
        sgK[s] = row * 64 + g * 8;
        sgV[s] = row * SEQ + g * 8;
    }
    int rd[4];
#pragma unroll
    for (int dc = 0; dc < 4; ++dc)
        rd[dc] = lq * 64 + (((dc * 2 + hi) ^ (lq & 7)) * 8);

    // Q frags for both halves: direct per-lane global loads (8 x 16B)
    bf16x8 qf0[4], qf1[4];
    {
        const bf16_t* Qrow0 = Q + ((size_t)bh * SEQ + q0 + w * 64 + lq) * HD;
        const bf16_t* Qrow1 = Qrow0 + 32 * HD;
#pragma unroll
        for (int dc = 0; dc < 4; ++dc) {
            qf0[dc] = *(const bf16x8*)&Qrow0[(dc * 2 + hi) * 8];
            qf1[dc] = *(const bf16x8*)&Qrow1[(dc * 2 + hi) * 8];
        }
    }

#define STAGEPH(BUF, PH)                                                       \
    {                                                                          \
        const bf16_t* Kp = Kg0 + (size_t)(PH) * 128 * HD;                      \
        const bf16_t* Vp = Vg0 + (PH) * 128;                                   \
        _Pragma("unroll")                                                      \
        for (int s = 0; s < 2; ++s) {                                          \
            gld16(&Ks[BUF][sl[s]], &Kp[sgK[s]]);                               \
            gld16(&Ks[BUF][4096 + sl[s]], &Kp[4096 + sgK[s]]);                 \
            gld16(&Vs[BUF][sl[s]], &Vp[sgV[s]]);                               \
            gld16(&Vs[BUF][4096 + sl[s]], &Vp[64 + sgV[s]]);                   \
        }                                                                      \
    }

    STAGEPH(0, 0)

    f32x16 Zf;
#pragma unroll
    for (int r = 0; r < 16; ++r) Zf[r] = 0.f;

    // Oacc[half][dblock]
    f32x16 O00, O01, O10, O11;
#pragma unroll
    for (int r = 0; r < 16; ++r) { O00[r] = 0.f; O01[r] = 0.f; O10[r] = 0.f; O11[r] = 0.f; }
    f32x2 lp0a = (f32x2){0.f, 0.f}, lp0b = (f32x2){0.f, 0.f};
    f32x2 lp1a = (f32x2){0.f, 0.f}, lp1b = (f32x2){0.f, 0.f};

#define PACKFRAG(SS, c2, PF, dstIdx)                                           \
        {                                                                      \
            unsigned pa = cvt_pk_bf16(SS[8 * (c2) + 0], SS[8 * (c2) + 1]);     \
            unsigned pb = cvt_pk_bf16(SS[8 * (c2) + 4], SS[8 * (c2) + 5]);     \
            unsigned pc = cvt_pk_bf16(SS[8 * (c2) + 2], SS[8 * (c2) + 3]);     \
            unsigned pd = cvt_pk_bf16(SS[8 * (c2) + 6], SS[8 * (c2) + 7]);     \
            asm volatile("v_permlane32_swap_b32 %0, %1" : "+v"(pa), "+v"(pb)); \
            asm volatile("v_permlane32_swap_b32 %0, %1" : "+v"(pc), "+v"(pd)); \
            union { unsigned u[4]; bf16x8 v; } pu;                             \
            pu.u[0] = pa; pu.u[1] = pc; pu.u[2] = pb; pu.u[3] = pd;            \
            PF[dstIdx] = pu.v;                                                 \
        }

#define MFMA32(A, B, C) __builtin_amdgcn_mfma_f32_32x32x16_bf16(A, B, C, 0, 0, 0)

#define EXPLP(SS, LP)                                                          \
        _Pragma("unroll")                                                      \
        for (int r = 0; r < 16; r += 2) {                                      \
            SS[r] = exp2_fast(SS[r]); SS[r + 1] = exp2_fast(SS[r + 1]);        \
            LP += (f32x2){SS[r], SS[r + 1]};                                   \
        }

#define ACORE2(BUF)                                                            \
    {                                                                          \
        f32x16 S0A0, S0A1, S0B0, S0B1, S1A0, S1A1, S1B0, S1B1;                 \
        __builtin_amdgcn_s_setprio(1);                                         \
        {                                                                      \
            bf16x8 a0 = *(const bf16x8*)&Ks[BUF][rd[0]];                       \
            bf16x8 a1 = *(const bf16x8*)&Ks[BUF][rd[0] + 2048];                \
            bf16x8 b0 = *(const bf16x8*)&Ks[BUF][rd[0] + 4096];                \
            bf16x8 b1 = *(const bf16x8*)&Ks[BUF][rd[0] + 6144];                \
            S0A0 = MFMA32(a0, qf0[0], Zf); S0A1 = MFMA32(a1, qf0[0], Zf);      \
            S0B0 = MFMA32(b0, qf0[0], Zf); S0B1 = MFMA32(b1, qf0[0], Zf);      \
            S1A0 = MFMA32(a0, qf1[0], Zf); S1A1 = MFMA32(a1, qf1[0], Zf);      \
            S1B0 = MFMA32(b0, qf1[0], Zf); S1B1 = MFMA32(b1, qf1[0], Zf);      \
        }                                                                      \
        _Pragma("unroll")                                                      \
        for (int dc = 1; dc < 4; ++dc) {                                       \
            bf16x8 a0 = *(const bf16x8*)&Ks[BUF][rd[dc]];                      \
            bf16x8 a1 = *(const bf16x8*)&Ks[BUF][rd[dc] + 2048];               \
            bf16x8 b0 = *(const bf16x8*)&Ks[BUF][rd[dc] + 4096];               \
            bf16x8 b1 = *(const bf16x8*)&Ks[BUF][rd[dc] + 6144];               \
            S0A0 = MFMA32(a0, qf0[dc], S0A0); S0A1 = MFMA32(a1, qf0[dc], S0A1); \
            S0B0 = MFMA32(b0, qf0[dc], S0B0); S0B1 = MFMA32(b1, qf0[dc], S0B1); \
            S1A0 = MFMA32(a0, qf1[dc], S1A0); S1A1 = MFMA32(a1, qf1[dc], S1A1); \
            S1B0 = MFMA32(b0, qf1[dc], S1B0); S1B1 = MFMA32(b1, qf1[dc], S1B1); \
        }                                                                      \
        __builtin_amdgcn_s_setprio(0);                                         \
        EXPLP(S0A0, lp0a) EXPLP(S0A1, lp0b) EXPLP(S0B0, lp0a) EXPLP(S0B1, lp0b) \
        EXPLP(S1A0, lp1a) EXPLP(S1A1, lp1b) EXPLP(S1B0, lp1a) EXPLP(S1B1, lp1b) \
        bf16x8 pf0[8], pf1[8];                                                 \
        PACKFRAG(S0A0, 0, pf0, 0) PACKFRAG(S0A0, 1, pf0, 1)                    \
        PACKFRAG(S0A1, 0, pf0, 2) PACKFRAG(S0A1, 1, pf0, 3)                    \
        PACKFRAG(S0B0, 0, pf0, 4) PACKFRAG(S0B0, 1, pf0, 5)                    \
        PACKFRAG(S0B1, 0, pf0, 6) PACKFRAG(S0B1, 1, pf0, 7)                    \
        PACKFRAG(S1A0, 0, pf1, 0) PACKFRAG(S1A0, 1, pf1, 1)                    \
        PACKFRAG(S1A1, 0, pf1, 2) PACKFRAG(S1A1, 1, pf1, 3)                    \
        PACKFRAG(S1B0, 0, pf1, 4) PACKFRAG(S1B0, 1, pf1, 5)                    \
        PACKFRAG(S1B1, 0, pf1, 6) PACKFRAG(S1B1, 1, pf1, 7)                    \
        __builtin_amdgcn_s_setprio(1);                                         \
        _Pragma("unroll")                                                      \
        for (int f = 0; f < 4; ++f) {                                          \
            bf16x8 vA0 = *(const bf16x8*)&Vs[BUF][rd[f]];                      \
            bf16x8 vA1 = *(const bf16x8*)&Vs[BUF][rd[f] + 2048];               \
            bf16x8 vB0 = *(const bf16x8*)&Vs[BUF][rd[f] + 4096];               \
            bf16x8 vB1 = *(const bf16x8*)&Vs[BUF][rd[f] + 6144];               \
            O00 = MFMA32(pf0[f], vA0, O00); O01 = MFMA32(pf0[f], vA1, O01);    \
            O10 = MFMA32(pf1[f], vA0, O10); O11 = MFMA32(pf1[f], vA1, O11);    \
            O00 = MFMA32(pf0[4 + f], vB0, O00); O01 = MFMA32(pf0[4 + f], vB1, O01); \
            O10 = MFMA32(pf1[4 + f], vB0, O10); O11 = MFMA32(pf1[4 + f], vB1, O11); \
        }                                                                      \
        __builtin_amdgcn_s_setprio(0);                                         \
    }

    for (int p = 0; p < 16; p += 2) {
        WAITV(0);
        BAR();
        STAGEPH(1, p + 1)
        ACORE2(0)
        WAITV(0);
        BAR();
        if (p < 14) STAGEPH(0, p + 2)
        ACORE2(1)
    }
#undef ACORE2
#undef EXPLP
#undef MFMA32
#undef PACKFRAG
#undef STAGEPH

    float lp0 = (lp0a[0] + lp0a[1]) + (lp0b[0] + lp0b[1]);
    float lp1 = (lp1a[0] + lp1a[1]) + (lp1b[0] + lp1b[1]);
    lp0 += __shfl_xor(lp0, 32);
    lp1 += __shfl_xor(lp1, 32);
    float rl0 = 1.0f / lp0, rl1 = 1.0f / lp1;

    // C/D layout: col = d = lane&31, row = q_loc = (r&3)+8*(r>>2)+4*hi
#pragma unroll
    for (int r = 0; r < 16; ++r) {
        int q_loc = (r & 3) + 8 * (r >> 2) + 4 * hi;
        float rr0 = __shfl(rl0, q_loc);
        float rr1 = __shfl(rl1, q_loc);
        int qrow0 = q0 + w * 64 + q_loc;
        size_t base0 = ((size_t)(b * SEQ + qrow0)) * EMB + h * 64;
        size_t base1 = base0 + (size_t)32 * EMB;  // half1 rows are +32
        O[base0 + lq] = (bf16_t)(O00[r] * rr0);
        O[base0 + 32 + lq] = (bf16_t)(O01[r] * rr0);
        O[base1 + lq] = (bf16_t)(O10[r] * rr1);
        O[base1 + 32 + lq] = (bf16_t)(O11[r] * rr1);
    }
}

// ---------------------------------------------------------------------------
extern "C" void kernel_launch(void* const* d_in, const int* in_sizes, int n_in,
                              void* d_out, int out_size, void* d_ws, size_t ws_size,
                              hipStream_t stream) {
    (void)in_sizes; (void)n_in; (void)out_size; (void)ws_size;
    const float* x  = (const float*)d_in[0];
    const float* Wq = (const float*)d_in[1];
    const float* bq = (const float*)d_in[2];
    const float* Wk = (const float*)d_in[3];
    const float* bk = (const float*)d_in[4];
    const float* Wv = (const float*)d_in[5];
    const float* bv = (const float*)d_in[6];
    const float* Wo = (const float*)d_in[7];
    const float* bo = (const float*)d_in[8];

    bf16_t* ws = (bf16_t*)d_ws;
    const size_t NELEM = (size_t)TOKENS * EMB;  // 4M
    const size_t WELEM = (size_t)EMB * EMB;     // 1M
    bf16_t* Qb  = ws;
    bf16_t* Kb  = ws + NELEM;
    bf16_t* Vtb = ws + 2 * NELEM;   // V^T written directly by QKV GEMM (mode 2)
    bf16_t* Ob  = ws + 3 * NELEM;
    bf16_t* xb  = ws + 4 * NELEM;
    bf16_t* Wt0 = ws + 5 * NELEM;   // Wt0..Wt2 contiguous -> fused N=3072 GEMM
    bf16_t* Wt1 = Wt0 + WELEM;
    bf16_t* Wt2 = Wt0 + 2 * WELEM;
    bf16_t* Wt3 = Wt0 + 3 * WELEM;  // total 48 MB of d_ws
    (void)Wt1; (void)Wt2;

    hipLaunchKernelGGL(prep_all, dim3(2048), dim3(256), 0, stream,
                       x, xb, Wq, Wk, Wv, Wo, Wt0, Wt1, Wt2, Wt3);
    // fused QKV, 8-phase 256x256: 192 blocks (16m x 12n), single round.
    hipLaunchKernelGGL((gemm8p<bf16_t>), dim3(192), dim3(512), 0, stream,
                       xb, Wt0, bq, bk, bv, Qb, Kb, Vtb,
                       1, 1, 2, 0.0450842204f, 1.0f, 1.0f,
                       4, 6, 3, 2);
    hipLaunchKernelGGL(attn_kernel, dim3(8, 32), dim3(256), 0, stream, Qb, Kb, Vtb, Ob);
    // O-proj: gemm256, 128 blocks, XCD c owns 2 m-tiles x all 8 n-tiles.
    hipLaunchKernelGGL((gemm256<float>), dim3(128), dim3(512), 0, stream,
                       Ob, Wt3, bo, bo, bo,
                       (float*)d_out, (float*)d_out, (float*)d_out,
                       0, 0, 0, 1.0f, 1.0f, 1.0f,
                       2, 7, 3, 8);
}

// Round 11
// 188.149 us; speedup vs baseline: 1.0452x; 1.0452x over previous
//
#include <hip/hip_runtime.h>
#include <hip/hip_bf16.h>

typedef __bf16 bf16_t;
typedef bf16_t bf16x8 __attribute__((ext_vector_type(8)));
typedef float f32x4 __attribute__((ext_vector_type(4)));
typedef float f32x2 __attribute__((ext_vector_type(2)));
typedef float f32x16 __attribute__((ext_vector_type(16)));

#define EMB 1024
#define HEADS 16
#define BATCH 2
#define SEQ 2048
#define HD 64
#define TOKENS (BATCH * SEQ)  // 4096

// async global->LDS, 16B per lane. LDS dest = wave-uniform base + lane*16.
__device__ __forceinline__ void gld16(bf16_t* lds_dst, const bf16_t* g_src) {
    __builtin_amdgcn_global_load_lds(
        (const __attribute__((address_space(1))) unsigned int*)g_src,
        (__attribute__((address_space(3))) unsigned int*)lds_dst, 16, 0, 0);
}

__device__ __forceinline__ unsigned cvt_pk_bf16(float lo, float hi) {
    unsigned r;
    asm("v_cvt_pk_bf16_f32 %0, %1, %2" : "=v"(r) : "v"(lo), "v"(hi));
    return r;
}

// 2^x. Q is pre-scaled by log2(e)/32 in the QKV GEMM, so softmax needs only 2^x.
__device__ __forceinline__ float exp2_fast(float x) {
#if __has_builtin(__builtin_amdgcn_exp2f)
    return __builtin_amdgcn_exp2f(x);
#else
    return __expf(x * 0.69314718056f);
#endif
}

// counted waits: keep prefetches in flight across raw barriers (T4).
#define WAITV(N) asm volatile("s_waitcnt vmcnt(" #N ")" ::: "memory")
#define WAITLGKM() asm volatile("s_waitcnt lgkmcnt(0)" ::: "memory")
#define BAR() __builtin_amdgcn_s_barrier()

// ---------------------------------------------------------------------------
// Merged prep: bid<1024 -> x fp32->bf16 (16 elems/thread);
//              bid>=1024 -> W[k][n] fp32 -> Wt[n][k] bf16 (64x64 tiles).
// ---------------------------------------------------------------------------
__global__ __launch_bounds__(256) void prep_all(
    const float* __restrict__ x, bf16_t* __restrict__ xb,
    const float* __restrict__ W0, const float* __restrict__ W1,
    const float* __restrict__ W2, const float* __restrict__ W3,
    bf16_t* __restrict__ T0, bf16_t* __restrict__ T1,
    bf16_t* __restrict__ T2, bf16_t* __restrict__ T3) {
    __shared__ __align__(16) bf16_t T[64][72];
    if (blockIdx.x < 1024) {
        size_t i = ((size_t)blockIdx.x * 256 + threadIdx.x) * 16;
        f32x4 v0 = *(const f32x4*)&x[i];
        f32x4 v1 = *(const f32x4*)&x[i + 4];
        f32x4 v2 = *(const f32x4*)&x[i + 8];
        f32x4 v3 = *(const f32x4*)&x[i + 12];
        bf16x8 o0, o1;
#pragma unroll
        for (int j = 0; j < 4; ++j) {
            o0[j] = (bf16_t)v0[j]; o0[4 + j] = (bf16_t)v1[j];
            o1[j] = (bf16_t)v2[j]; o1[4 + j] = (bf16_t)v3[j];
        }
        *(bf16x8*)&xb[i] = o0;
        *(bf16x8*)&xb[i + 8] = o1;
        return;
    }
    int t = blockIdx.x - 1024;
    int z = t >> 8, rid = t & 255;
    const float* src = (z == 0) ? W0 : (z == 1) ? W1 : (z == 2) ? W2 : W3;
    bf16_t* dst = (z == 0) ? T0 : (z == 1) ? T1 : (z == 2) ? T2 : T3;
    int k0 = (rid >> 4) * 64, n0 = (rid & 15) * 64;
    int r = threadIdx.x >> 2, c4 = (threadIdx.x & 3) * 16;
    f32x4 v[4];
#pragma unroll
    for (int q = 0; q < 4; ++q)
        v[q] = *(const f32x4*)&src[(size_t)(k0 + r) * 1024 + n0 + c4 + q * 4];
#pragma unroll
    for (int j = 0; j < 16; ++j) T[c4 + j][r] = (bf16_t)v[j >> 2][j & 3];
    __syncthreads();
    bf16x8 o0 = *(const bf16x8*)&T[r][c4];
    bf16x8 o1 = *(const bf16x8*)&T[r][c4 + 8];
    *(bf16x8*)&dst[(size_t)(n0 + r) * 1024 + k0 + c4] = o0;
    *(bf16x8*)&dst[(size_t)(n0 + r) * 1024 + k0 + c4 + 8] = o1;
}

// ---------------------------------------------------------------------------
// gemm8p: m201-style 8-phase GEMM. BM=BN=256 BK=64, 512 thr (8 waves 2Mx4N,
// wave tile 128x64). LDS = 2 bufs x (A 32K + B 32K) = 128 KB. (unchanged R8)
// ---------------------------------------------------------------------------
template <typename TO>
__global__ __launch_bounds__(512) void gemm8p(
    const bf16_t* __restrict__ A, const bf16_t* __restrict__ W,
    const float* __restrict__ b0, const float* __restrict__ b1, const float* __restrict__ b2,
    TO* __restrict__ o0, TO* __restrict__ o1, TO* __restrict__ o2,
    int md0, int md1, int md2, float sc0, float sc1, float sc2,
    int XMP, int XNP, int CXM, int CXS) {
    __shared__ __align__(16) bf16_t As[2][256 * 64];  // 64 KB
    __shared__ __align__(16) bf16_t Bs[2][256 * 64];  // 64 KB

    const int tid = threadIdx.x, w = tid >> 6, lane = tid & 63;
    const int quad = lane >> 4, cc = lane & 15;
    const int wr = w >> 2, wc = w & 3;  // 2M x 4N

    const int lin = blockIdx.x;
    const int xc = lin & 7, t = lin >> 3;
    const int mi = (xc & CXM) * XMP + (t % XMP);
    const int ni = (xc >> CXS) * XNP + (t / XMP);
    const int m0 = mi * 256, n0 = ni * 256;

    const int z = n0 >> 10;
    const float* bias = (z == 0) ? b0 : (z == 1) ? b1 : b2;
    TO* out = (z == 0) ? o0 : (z == 1) ? o1 : o2;
    const int mode = (z == 0) ? md0 : (z == 1) ? md1 : md2;
    const float scale = (z == 0) ? sc0 : (z == 1) ? sc1 : sc2;
    const int nz = n0 & 1023;

    f32x4 acc[8][4];
#pragma unroll
    for (int i = 0; i < 8; ++i)
#pragma unroll
        for (int j = 0; j < 4; ++j) acc[i][j] = (f32x4){0.f, 0.f, 0.f, 0.f};

    const int r8 = lane >> 3, sg = lane & 7;
    const int g8 = (sg ^ r8) * 8;  // pre-swizzled source chunk offset (elems)
    const bf16_t* Ag = A + (size_t)m0 * 1024;
    const bf16_t* Bg = W + (size_t)n0 * 1024;

#define ST_A(BUF, TILE, H)                                                     \
    {                                                                          \
        _Pragma("unroll")                                                      \
        for (int s = 0; s < 2; ++s) {                                          \
            int rg = (H) * 128 + (w * 2 + s) * 8;                              \
            gld16(&As[BUF][rg * 64],                                           \
                  &Ag[(size_t)(rg + r8) * 1024 + (TILE) * 64 + g8]);           \
        }                                                                      \
    }
#define ST_B(BUF, TILE, H)                                                     \
    {                                                                          \
        _Pragma("unroll")                                                      \
        for (int s = 0; s < 2; ++s) {                                          \
            int rg = (H) * 128 + (w * 2 + s) * 8;                              \
            gld16(&Bs[BUF][rg * 64],                                           \
                  &Bg[(size_t)(rg + r8) * 1024 + (TILE) * 64 + g8]);           \
        }                                                                      \
    }

    const int soq = (quad ^ (cc & 7)) * 8;
    int rArow[8], rBrow[4];
#pragma unroll
    for (int mt = 0; mt < 8; ++mt) rArow[mt] = (wr * 128 + mt * 16 + cc) * 64;
#pragma unroll
    for (int nt = 0; nt < 4; ++nt) rBrow[nt] = (wc * 64 + nt * 16 + cc) * 64;

    bf16x8 bfr[4][2];
#define RD_B(BUF)                                                              \
    {                                                                          \
        _Pragma("unroll")                                                      \
        for (int nt = 0; nt < 4; ++nt) {                                       \
            bfr[nt][0] = *(const bf16x8*)&Bs[BUF][rBrow[nt] + soq];            \
            bfr[nt][1] = *(const bf16x8*)&Bs[BUF][rBrow[nt] + (soq ^ 32)];     \
        }                                                                      \
    }

#define PHASE(BUF, Q, STG)                                                     \
    {                                                                          \
        bf16x8 af0a = *(const bf16x8*)&As[BUF][rArow[(Q) * 2] + soq];          \
        bf16x8 af0b = *(const bf16x8*)&As[BUF][rArow[(Q) * 2] + (soq ^ 32)];   \
        bf16x8 af1a = *(const bf16x8*)&As[BUF][rArow[(Q) * 2 + 1] + soq];      \
        bf16x8 af1b = *(const bf16x8*)&As[BUF][rArow[(Q) * 2 + 1] + (soq ^ 32)]; \
        STG;                                                                   \
        WAITLGKM();                                                            \
        __builtin_amdgcn_sched_barrier(0);                                     \
        __builtin_amdgcn_s_setprio(1);                                         \
        _Pragma("unroll")                                                      \
        for (int nt = 0; nt < 4; ++nt) {                                       \
            acc[(Q) * 2][nt] = __builtin_amdgcn_mfma_f32_16x16x32_bf16(        \
                af0a, bfr[nt][0], acc[(Q) * 2][nt], 0, 0, 0);                  \
            acc[(Q) * 2][nt] = __builtin_amdgcn_mfma_f32_16x16x32_bf16(        \
                af0b, bfr[nt][1], acc[(Q) * 2][nt], 0, 0, 0);                  \
            acc[(Q) * 2 + 1][nt] = __builtin_amdgcn_mfma_f32_16x16x32_bf16(    \
                af1a, bfr[nt][0], acc[(Q) * 2 + 1][nt], 0, 0, 0);              \
            acc[(Q) * 2 + 1][nt] = __builtin_amdgcn_mfma_f32_16x16x32_bf16(    \
                af1b, bfr[nt][1], acc[(Q) * 2 + 1][nt], 0, 0, 0);              \
        }                                                                      \
        __builtin_amdgcn_s_setprio(0);                                         \
    }

    ST_A(0, 0, 0) ST_A(0, 0, 1) ST_B(0, 0, 0) ST_B(0, 0, 1)
    ST_B(1, 1, 0) ST_B(1, 1, 1)

    for (int i = 0; i < 8; ++i) {
        WAITV(4);
        BAR();
        RD_B(0)
        PHASE(0, 0, ST_A(1, 2 * i + 1, 0))
        BAR();
        PHASE(0, 1, ST_A(1, 2 * i + 1, 1))
        BAR();
        PHASE(0, 2, if (i < 7) ST_B(0, 2 * i + 2, 0))
        BAR();
        PHASE(0, 3, if (i < 7) ST_B(0, 2 * i + 2, 1))
        if (i < 7) { WAITV(4); } else { WAITV(0); }
        BAR();
        RD_B(1)
        PHASE(1, 0, if (i < 7) ST_A(0, 2 * i + 2, 0))
        BAR();
        PHASE(1, 1, if (i < 7) ST_A(0, 2 * i + 2, 1))
        BAR();
        PHASE(1, 2, if (i < 7) ST_B(1, 2 * i + 3, 0))
        BAR();
        PHASE(1, 3, if (i < 7) ST_B(1, 2 * i + 3, 1))
    }
#undef PHASE
#undef RD_B
#undef ST_A
#undef ST_B

    typedef TO TOx4 __attribute__((ext_vector_type(4)));
#pragma unroll
    for (int nt = 0; nt < 4; ++nt) {
        int colz = nz + wc * 64 + nt * 16 + cc;
        float bv = bias[colz];
#pragma unroll
        for (int mt = 0; mt < 8; ++mt) {
            if (mode == 2) {
                int row = m0 + wr * 128 + mt * 16 + quad * 4;
                int bb = row >> 11, n = row & 2047;
                int hh = colz >> 6, d = colz & 63;
                TOx4 pk;
#pragma unroll
                for (int r = 0; r < 4; ++r)
                    pk[r] = (TO)((acc[mt][nt][r] + bv) * scale);
                *(TOx4*)&out[((size_t)(bb * HEADS + hh) * HD + d) * SEQ + n] = pk;
            } else {
#pragma unroll
                for (int r = 0; r < 4; ++r) {
                    int row = m0 + wr * 128 + mt * 16 + quad * 4 + r;
                    float v = (acc[mt][nt][r] + bv) * scale;
                    size_t idx;
                    if (mode == 0) {
                        idx = (size_t)row * 1024 + colz;
                    } else {
                        int bb = row >> 11, n = row & 2047;
                        int hh = colz >> 6, d = colz & 63;
                        idx = ((size_t)(bb * HEADS + hh) * SEQ + n) * HD + d;
                    }
                    out[idx] = (TO)v;
                }
            }
        }
    }
}

// ---------------------------------------------------------------------------
// GEMM v2 (kept for O-proj): BM=256 BN=128 BK=64, 512 thr, 3 bufs, vmcnt(6).
// ---------------------------------------------------------------------------
template <typename TO>
__global__ __launch_bounds__(512) void gemm256(
    const bf16_t* __restrict__ A, const bf16_t* __restrict__ W,
    const float* __restrict__ b0, const float* __restrict__ b1, const float* __restrict__ b2,
    TO* __restrict__ o0, TO* __restrict__ o1, TO* __restrict__ o2,
    int md0, int md1, int md2, float sc0, float sc1, float sc2,
    int MP, int CM, int CSH, int NP) {
    __shared__ __align__(16) bf16_t As[3][256 * 64];  // 96 KB
    __shared__ __align__(16) bf16_t Bs[3][128 * 64];  // 48 KB

    const int tid = threadIdx.x, w = tid >> 6, lane = tid & 63;
    const int quad = lane >> 4, c = lane & 15;
    const int wm = (w >> 1) * 64, wn = (w & 1) * 64;

    const int lin = blockIdx.x;
    const int xc = lin & 7, t = lin >> 3;
    const int mi = MP * (xc & CM) + (t % MP);
    const int ni = NP * (xc >> CSH) + (t / MP);
    const int m0 = mi * 256, n0 = ni * 128;

    const int z = n0 >> 10;
    const float* bias = (z == 0) ? b0 : (z == 1) ? b1 : b2;
    TO* out = (z == 0) ? o0 : (z == 1) ? o1 : o2;
    const int mode = (z == 0) ? md0 : (z == 1) ? md1 : md2;
    const float scale = (z == 0) ? sc0 : (z == 1) ? sc1 : sc2;
    const int nz = n0 & 1023;

    f32x4 acc[4][4];
#pragma unroll
    for (int i = 0; i < 4; ++i)
#pragma unroll
        for (int j = 0; j < 4; ++j) acc[i][j] = (f32x4){0.f, 0.f, 0.f, 0.f};

    const int r8 = lane >> 3, sg = lane & 7;
    const int g8 = (sg ^ r8) * 8;
    const bf16_t* Ag = A + (size_t)m0 * 1024;
    const bf16_t* Bg = W + (size_t)n0 * 1024;
    int gA[4], lA[4], gB[2], lB[2];
#pragma unroll
    for (int s = 0; s < 4; ++s) {
        lA[s] = (w * 32 + s * 8) * 64;
        gA[s] = (w * 32 + s * 8 + r8) * 1024 + g8;
    }
#pragma unroll
    for (int s = 0; s < 2; ++s) {
        lB[s] = (w * 16 + s * 8) * 64;
        gB[s] = (w * 16 + s * 8 + r8) * 1024 + g8;
    }

    const int so = (quad ^ (c & 7)) * 8;
    int rA[4], rB[4];
#pragma unroll
    for (int i = 0; i < 4; ++i) {
        rA[i] = (wm + i * 16 + c) * 64;
        rB[i] = (wn + i * 16 + c) * 64;
    }

#define STAGE(BUF, T)                                                          \
    {                                                                          \
        int kn = (T) * 64;                                                     \
        _Pragma("unroll")                                                      \
        for (int s = 0; s < 4; ++s) gld16(&As[BUF][lA[s]], &Ag[gA[s] + kn]);   \
        _Pragma("unroll")                                                      \
        for (int s = 0; s < 2; ++s) gld16(&Bs[BUF][lB[s]], &Bg[gB[s] + kn]);   \
    }

#define FRAGS(CUR)                                                             \
    {                                                                          \
        _Pragma("unroll")                                                      \
        for (int ks = 0; ks < 2; ++ks) {                                       \
            int sk = so ^ (ks << 5);                                           \
            bf16x8 af[4], bfv[4];                                              \
            _Pragma("unroll")                                                  \
            for (int i = 0; i < 4; ++i)                                        \
                af[i] = *(const bf16x8*)&As[CUR][rA[i] + sk];                  \
            _Pragma("unroll")                                                  \
            for (int i = 0; i < 4; ++i)                                        \
                bfv[i] = *(const bf16x8*)&Bs[CUR][rB[i] + sk];                 \
            __builtin_amdgcn_s_setprio(1);                                     \
            _Pragma("unroll")                                                  \
            for (int mt = 0; mt < 4; ++mt)                                     \
                _Pragma("unroll")                                              \
                for (int nt = 0; nt < 4; ++nt)                                 \
                    acc[mt][nt] = __builtin_amdgcn_mfma_f32_16x16x32_bf16(     \
                        af[mt], bfv[nt], acc[mt][nt], 0, 0, 0);                \
            __builtin_amdgcn_s_setprio(0);                                     \
        }                                                                      \
    }

#define GSTEP(T, CUR)                                                          \
    {                                                                          \
        WAITV(6);                                                              \
        BAR();                                                                 \
        STAGE(((CUR) + 2) % 3, (T) + 2)                                        \
        FRAGS(CUR)                                                             \
    }

    STAGE(0, 0)
    STAGE(1, 1)
    for (int T = 0; T < 12; T += 3) {
        GSTEP(T, 0)
        GSTEP(T + 1, 1)
        GSTEP(T + 2, 2)
    }
    GSTEP(12, 0)
    GSTEP(13, 1)
    WAITV(6); BAR(); FRAGS(2)
    WAITV(0); BAR(); FRAGS(0)
#undef GSTEP
#undef FRAGS
#undef STAGE

    typedef TO TOx4 __attribute__((ext_vector_type(4)));
#pragma unroll
    for (int nt = 0; nt < 4; ++nt) {
        int colz = nz + wn + nt * 16 + c;
        float bv = bias[colz];
#pragma unroll
        for (int mt = 0; mt < 4; ++mt) {
            if (mode == 2) {
                int row = m0 + wm + mt * 16 + quad * 4;
                int bb = row >> 11, n = row & 2047;
                int hh = colz >> 6, d = colz & 63;
                TOx4 pk;
#pragma unroll
                for (int r = 0; r < 4; ++r)
                    pk[r] = (TO)((acc[mt][nt][r] + bv) * scale);
                *(TOx4*)&out[((size_t)(bb * HEADS + hh) * HD + d) * SEQ + n] = pk;
            } else {
#pragma unroll
                for (int r = 0; r < 4; ++r) {
                    int row = m0 + wm + mt * 16 + quad * 4 + r;
                    float v = (acc[mt][nt][r] + bv) * scale;
                    size_t idx;
                    if (mode == 0) {
                        idx = (size_t)row * 1024 + colz;
                    } else {
                        int bb = row >> 11, n = row & 2047;
                        int hh = colz >> 6, d = colz & 63;
                        idx = ((size_t)(bb * HEADS + hh) * SEQ + n) * HD + d;
                    }
                    out[idx] = (TO)v;
                }
            }
        }
    }
}

// ---------------------------------------------------------------------------
// Flash attention (R8 version restored): 32x32 MFMA, swapped QK^T,
// in-register softmax, KVBLK=128 (2 tiles/phase), 16 phases, dbuf, counted
// waits. 2 blocks/CU -> 2 waves/SIMD (TLP is required: R10's 1-wave/SIMD
// variant halved LDS traffic but cost +27us of exposed latency).
// ---------------------------------------------------------------------------
__global__ __launch_bounds__(256, 2) void attn_kernel(
    const bf16_t* __restrict__ Q, const bf16_t* __restrict__ K,
    const bf16_t* __restrict__ Vt, bf16_t* __restrict__ O) {
    __shared__ __align__(16) bf16_t Ks[2][2 * 64 * 64];   // 32 KB
    __shared__ __align__(16) bf16_t Vs[2][2 * 64 * 64];   // 32 KB

    const int tid = threadIdx.x, w = tid >> 6, lane = tid & 63;
    const int hi = lane >> 5, lq = lane & 31;

    const int lin = blockIdx.x + (blockIdx.y << 4);
    const int xcd = lin & 7, slot = lin >> 3;
    const int bh = xcd + ((slot >> 4) << 3);
    const int q0 = (slot & 15) << 7;
    const int b = bh >> 4, h = bh & 15;

    const int srow8 = lane >> 3, sch = lane & 7;

    const bf16_t* Kg0 = K + (size_t)bh * SEQ * HD;
    const bf16_t* Vg0 = Vt + (size_t)bh * HD * SEQ;

    int sl[2], sgK[2], sgV[2];
#pragma unroll
    for (int s = 0; s < 2; ++s) {
        int rg = (w * 2 + s) * 8;
        int row = rg + srow8;
        int g = sch ^ (row & 7);
        sl[s] = rg * 64;
        sgK[s] = row * 64 + g * 8;
        sgV[s] = row * SEQ + g * 8;
    }
    int rd[4];
#pragma unroll
    for (int dc = 0; dc < 4; ++dc)
        rd[dc] = lq * 64 + (((dc * 2 + hi) ^ (lq & 7)) * 8);

    bf16x8 qf[4];
    {
        const bf16_t* Qrow = Q + ((size_t)bh * SEQ + q0 + w * 32 + lq) * HD;
#pragma unroll
        for (int dc = 0; dc < 4; ++dc)
            qf[dc] = *(const bf16x8*)&Qrow[(dc * 2 + hi) * 8];
    }

#define STAGEPH(BUF, PH)                                                       \
    {                                                                          \
        const bf16_t* Kp = Kg0 + (size_t)(PH) * 128 * HD;                      \
        const bf16_t* Vp = Vg0 + (PH) * 128;                                   \
        _Pragma("unroll")                                                      \
        for (int s = 0; s < 2; ++s) {                                          \
            gld16(&Ks[BUF][sl[s]], &Kp[sgK[s]]);                               \
            gld16(&Ks[BUF][4096 + sl[s]], &Kp[4096 + sgK[s]]);                 \
            gld16(&Vs[BUF][sl[s]], &Vp[sgV[s]]);                               \
            gld16(&Vs[BUF][4096 + sl[s]], &Vp[64 + sgV[s]]);                   \
        }                                                                      \
    }

    STAGEPH(0, 0)

    f32x16 Zf;
#pragma unroll
    for (int r = 0; r < 16; ++r) Zf[r] = 0.f;

    f32x16 Oacc0, Oacc1;
#pragma unroll
    for (int r = 0; r < 16; ++r) { Oacc0[r] = 0.f; Oacc1[r] = 0.f; }
    f32x2 lpA = (f32x2){0.f, 0.f}, lpB = (f32x2){0.f, 0.f};

#define PACKFRAG(SS, c2, dstIdx)                                               \
        {                                                                      \
            unsigned pa = cvt_pk_bf16(SS[8 * (c2) + 0], SS[8 * (c2) + 1]);     \
            unsigned pb = cvt_pk_bf16(SS[8 * (c2) + 4], SS[8 * (c2) + 5]);     \
            unsigned pc = cvt_pk_bf16(SS[8 * (c2) + 2], SS[8 * (c2) + 3]);     \
            unsigned pd = cvt_pk_bf16(SS[8 * (c2) + 6], SS[8 * (c2) + 7]);     \
            asm volatile("v_permlane32_swap_b32 %0, %1" : "+v"(pa), "+v"(pb)); \
            asm volatile("v_permlane32_swap_b32 %0, %1" : "+v"(pc), "+v"(pd)); \
            union { unsigned u[4]; bf16x8 v; } pu;                             \
            pu.u[0] = pa; pu.u[1] = pc; pu.u[2] = pb; pu.u[3] = pd;            \
            pf[dstIdx] = pu.v;                                                 \
        }

#define MFMA32(A, B, C) __builtin_amdgcn_mfma_f32_32x32x16_bf16(A, B, C, 0, 0, 0)

#define ACORE2(BUF)                                                            \
    {                                                                          \
        f32x16 SA0, SA1, SB0, SB1;                                             \
        __builtin_amdgcn_s_setprio(1);                                         \
        {                                                                      \
            bf16x8 a0 = *(const bf16x8*)&Ks[BUF][rd[0]];                       \
            bf16x8 a1 = *(const bf16x8*)&Ks[BUF][rd[0] + 2048];                \
            bf16x8 b0 = *(const bf16x8*)&Ks[BUF][rd[0] + 4096];                \
            bf16x8 b1 = *(const bf16x8*)&Ks[BUF][rd[0] + 6144];                \
            SA0 = MFMA32(a0, qf[0], Zf);                                       \
            SA1 = MFMA32(a1, qf[0], Zf);                                       \
            SB0 = MFMA32(b0, qf[0], Zf);                                       \
            SB1 = MFMA32(b1, qf[0], Zf);                                       \
        }                                                                      \
        _Pragma("unroll")                                                      \
        for (int dc = 1; dc < 4; ++dc) {                                       \
            bf16x8 a0 = *(const bf16x8*)&Ks[BUF][rd[dc]];                      \
            bf16x8 a1 = *(const bf16x8*)&Ks[BUF][rd[dc] + 2048];               \
            bf16x8 b0 = *(const bf16x8*)&Ks[BUF][rd[dc] + 4096];               \
            bf16x8 b1 = *(const bf16x8*)&Ks[BUF][rd[dc] + 6144];               \
            SA0 = MFMA32(a0, qf[dc], SA0);                                     \
            SA1 = MFMA32(a1, qf[dc], SA1);                                     \
            SB0 = MFMA32(b0, qf[dc], SB0);                                     \
            SB1 = MFMA32(b1, qf[dc], SB1);                                     \
        }                                                                      \
        __builtin_amdgcn_s_setprio(0);                                         \
        _Pragma("unroll")                                                      \
        for (int r = 0; r < 16; r += 2) {                                      \
            SA0[r] = exp2_fast(SA0[r]); SA0[r + 1] = exp2_fast(SA0[r + 1]);    \
            lpA += (f32x2){SA0[r], SA0[r + 1]};                                \
            SA1[r] = exp2_fast(SA1[r]); SA1[r + 1] = exp2_fast(SA1[r + 1]);    \
            lpB += (f32x2){SA1[r], SA1[r + 1]};                                \
            SB0[r] = exp2_fast(SB0[r]); SB0[r + 1] = exp2_fast(SB0[r + 1]);    \
            lpA += (f32x2){SB0[r], SB0[r + 1]};                                \
            SB1[r] = exp2_fast(SB1[r]); SB1[r + 1] = exp2_fast(SB1[r + 1]);    \
            lpB += (f32x2){SB1[r], SB1[r + 1]};                                \
        }                                                                      \
        bf16x8 pf[8];                                                          \
        PACKFRAG(SA0, 0, 0) PACKFRAG(SA0, 1, 1)                                \
        PACKFRAG(SA1, 0, 2) PACKFRAG(SA1, 1, 3)                                \
        PACKFRAG(SB0, 0, 4) PACKFRAG(SB0, 1, 5)                                \
        PACKFRAG(SB1, 0, 6) PACKFRAG(SB1, 1, 7)                                \
        __builtin_amdgcn_s_setprio(1);                                         \
        _Pragma("unroll")                                                      \
        for (int f = 0; f < 4; ++f) {                                          \
            bf16x8 vA0 = *(const bf16x8*)&Vs[BUF][rd[f]];                      \
            bf16x8 vA1 = *(const bf16x8*)&Vs[BUF][rd[f] + 2048];               \
            bf16x8 vB0 = *(const bf16x8*)&Vs[BUF][rd[f] + 4096];               \
            bf16x8 vB1 = *(const bf16x8*)&Vs[BUF][rd[f] + 6144];               \
            Oacc0 = MFMA32(pf[f], vA0, Oacc0);                                 \
            Oacc1 = MFMA32(pf[f], vA1, Oacc1);                                 \
            Oacc0 = MFMA32(pf[4 + f], vB0, Oacc0);                             \
            Oacc1 = MFMA32(pf[4 + f], vB1, Oacc1);                             \
        }                                                                      \
        __builtin_amdgcn_s_setprio(0);                                         \
    }

    for (int p = 0; p < 16; p += 2) {
        WAITV(0);
        BAR();
        STAGEPH(1, p + 1)
        ACORE2(0)
        WAITV(0);
        BAR();
        if (p < 14) STAGEPH(0, p + 2)
        ACORE2(1)
    }
#undef ACORE2
#undef MFMA32
#undef PACKFRAG
#undef STAGEPH

    float lp = (lpA[0] + lpA[1]) + (lpB[0] + lpB[1]);
    lp += __shfl_xor(lp, 32);
    float rl = 1.0f / lp;

#pragma unroll
    for (int r = 0; r < 16; ++r) {
        int q_loc = (r & 3) + 8 * (r >> 2) + 4 * hi;
        float rr = __shfl(rl, q_loc);
        int qrow = q0 + w * 32 + q_loc;
        size_t base = ((size_t)(b * SEQ + qrow)) * EMB + h * 64;
        O[base + lq] = (bf16_t)(Oacc0[r] * rr);
        O[base + 32 + lq] = (bf16_t)(Oacc1[r] * rr);
    }
}

// ---------------------------------------------------------------------------
extern "C" void kernel_launch(void* const* d_in, const int* in_sizes, int n_in,
                              void* d_out, int out_size, void* d_ws, size_t ws_size,
                              hipStream_t stream) {
    (void)in_sizes; (void)n_in; (void)out_size; (void)ws_size;
    const float* x  = (const float*)d_in[0];
    const float* Wq = (const float*)d_in[1];
    const float* bq = (const float*)d_in[2];
    const float* Wk = (const float*)d_in[3];
    const float* bk = (const float*)d_in[4];
    const float* Wv = (const float*)d_in[5];
    const float* bv = (const float*)d_in[6];
    const float* Wo = (const float*)d_in[7];
    const float* bo = (const float*)d_in[8];

    bf16_t* ws = (bf16_t*)d_ws;
    const size_t NELEM = (size_t)TOKENS * EMB;  // 4M
    const size_t WELEM = (size_t)EMB * EMB;     // 1M
    bf16_t* Qb  = ws;
    bf16_t* Kb  = ws + NELEM;
    bf16_t* Vtb = ws + 2 * NELEM;   // V^T written directly by QKV GEMM (mode 2)
    bf16_t* Ob  = ws + 3 * NELEM;
    bf16_t* xb  = ws + 4 * NELEM;
    bf16_t* Wt0 = ws + 5 * NELEM;   // Wt0..Wt2 contiguous -> fused N=3072 GEMM
    bf16_t* Wt1 = Wt0 + WELEM;
    bf16_t* Wt2 = Wt0 + 2 * WELEM;
    bf16_t* Wt3 = Wt0 + 3 * WELEM;  // total 48 MB of d_ws
    (void)Wt1; (void)Wt2;

    hipLaunchKernelGGL(prep_all, dim3(2048), dim3(256), 0, stream,
                       x, xb, Wq, Wk, Wv, Wo, Wt0, Wt1, Wt2, Wt3);
    // fused QKV, 8-phase 256x256: 192 blocks (16m x 12n), single round.
    hipLaunchKernelGGL((gemm8p<bf16_t>), dim3(192), dim3(512), 0, stream,
                       xb, Wt0, bq, bk, bv, Qb, Kb, Vtb,
                       1, 1, 2, 0.0450842204f, 1.0f, 1.0f,
                       4, 6, 3, 2);
    hipLaunchKernelGGL(attn_kernel, dim3(16, 32), dim3(256), 0, stream, Qb, Kb, Vtb, Ob);
    // O-proj: gemm256, 128 blocks, XCD c owns 2 m-tiles x all 8 n-tiles.
    hipLaunchKernelGGL((gemm256<float>), dim3(128), dim3(512), 0, stream,
                       Ob, Wt3, bo, bo, bo,
                       (float*)d_out, (float*)d_out, (float*)d_out,
                       0, 0, 0, 1.0f, 1.0f, 1.0f,
                       2, 7, 3, 8);
}